// Round 1
// baseline (98.590 us; speedup 1.0000x reference)
//
#include <hip/hip_runtime.h>
#include <math.h>

#define BB 8
#define NN 900
#define CC 256
#define HEADS 8
#define PP 4
#define BEV_H 200
#define BEV_W 200
#define HD 32
#define RADIUS 0.2f

// ---------------- Kernel 1: projections + softmax + bilinear sampling ----------------
__global__ __launch_bounds__(256) void deform_sample_kernel(
    const float* __restrict__ query,      // [B,N,C]
    const float* __restrict__ memory,     // [B, H*W, C]
    const float* __restrict__ refpts,     // [B,N,2]
    const float* __restrict__ w_off,      // [C, 64]
    const float* __restrict__ b_off,      // [64]
    const float* __restrict__ w_wt,       // [C, 32]
    const float* __restrict__ b_wt,       // [32]
    float* __restrict__ fused)            // [B*N, C]
{
    const int bn = blockIdx.x;            // 0 .. B*N-1
    const int b  = bn / NN;
    const int t  = threadIdx.x;

    __shared__ float s_q[CC];
    __shared__ float s_off[HEADS * PP * 2];
    __shared__ float s_wt[HEADS * PP];
    __shared__ float s_w[HEADS * PP];
    __shared__ int   s_x0[HEADS * PP], s_y0[HEADS * PP];
    __shared__ float s_fx[HEADS * PP], s_fy[HEADS * PP];

    s_q[t] = query[(size_t)bn * CC + t];
    __syncthreads();

    // projections: 64 offset logits + 32 weight logits
    if (t < 64) {
        float acc = b_off[t];
        for (int c = 0; c < CC; ++c) acc += s_q[c] * w_off[c * 64 + t];
        s_off[t] = tanhf(acc) * RADIUS;
    } else if (t < 96) {
        const int j = t - 64;
        float acc = b_wt[j];
        for (int c = 0; c < CC; ++c) acc += s_q[c] * w_wt[c * 32 + j];
        s_wt[j] = acc;
    }
    __syncthreads();

    // softmax over P per head
    if (t < HEADS) {
        float m = s_wt[t * PP];
        #pragma unroll
        for (int p = 1; p < PP; ++p) m = fmaxf(m, s_wt[t * PP + p]);
        float e[PP];
        float sum = 0.f;
        #pragma unroll
        for (int p = 0; p < PP; ++p) { e[p] = expf(s_wt[t * PP + p] - m); sum += e[p]; }
        float inv = 1.f / sum;
        #pragma unroll
        for (int p = 0; p < PP; ++p) s_w[t * PP + p] = e[p] * inv;
    }
    // sampling coordinates per (head, point)
    if (t < HEADS * PP) {
        const float rx = refpts[(size_t)bn * 2 + 0];
        const float ry = refpts[(size_t)bn * 2 + 1];
        const float lx = rx + s_off[t * 2 + 0];
        const float ly = ry + s_off[t * 2 + 1];
        const float x = lx * (float)BEV_W - 0.5f;
        const float y = ly * (float)BEV_H - 0.5f;
        const float x0f = floorf(x), y0f = floorf(y);
        s_x0[t] = (int)x0f; s_y0[t] = (int)y0f;
        s_fx[t] = x - x0f;  s_fy[t] = y - y0f;
    }
    __syncthreads();

    // bilinear gather + weighted sum over P.  thread t -> (head h, channel ch)
    const int h  = t >> 5;
    const int ch = t & 31;
    const float* mem_b = memory + (size_t)b * (BEV_H * BEV_W) * CC + h * HD + ch;
    float acc = 0.f;
    #pragma unroll
    for (int p = 0; p < PP; ++p) {
        const int i = h * PP + p;
        const int x0 = s_x0[i], y0 = s_y0[i];
        const float fx = s_fx[i], fy = s_fy[i];
        const float w = s_w[i];
        const bool xv0 = (x0 >= 0) & (x0 < BEV_W);
        const bool xv1 = (x0 + 1 >= 0) & (x0 + 1 < BEV_W);
        const bool yv0 = (y0 >= 0) & (y0 < BEV_H);
        const bool yv1 = (y0 + 1 >= 0) & (y0 + 1 < BEV_H);
        float v00 = 0.f, v01 = 0.f, v10 = 0.f, v11 = 0.f;
        if (xv0 && yv0) v00 = mem_b[(size_t)(y0 * BEV_W + x0) * CC];
        if (xv1 && yv0) v01 = mem_b[(size_t)(y0 * BEV_W + x0 + 1) * CC];
        if (xv0 && yv1) v10 = mem_b[(size_t)((y0 + 1) * BEV_W + x0) * CC];
        if (xv1 && yv1) v11 = mem_b[(size_t)((y0 + 1) * BEV_W + x0 + 1) * CC];
        const float s = v00 * (1.f - fx) * (1.f - fy)
                      + v01 * fx * (1.f - fy)
                      + v10 * (1.f - fx) * fy
                      + v11 * fx * fy;
        acc += w * s;
    }
    fused[(size_t)bn * CC + t] = acc;
}

// ---------------- Kernel 2: out = fused @ w_out + b_out ----------------
#define ROWS 16
__global__ __launch_bounds__(256) void out_gemm_kernel(
    const float* __restrict__ fused,   // [B*N, C]
    const float* __restrict__ w_out,   // [C, C]
    const float* __restrict__ b_out,   // [C]
    float* __restrict__ out)           // [B*N, C]
{
    const int row0 = blockIdx.x * ROWS;
    const int col  = threadIdx.x;

    __shared__ float s_f[ROWS][64];
    float acc[ROWS];
    #pragma unroll
    for (int r = 0; r < ROWS; ++r) acc[r] = 0.f;

    for (int k0 = 0; k0 < CC; k0 += 64) {
        __syncthreads();
        for (int e = threadIdx.x; e < ROWS * 64; e += 256) {
            const int r = e >> 6, kk = e & 63;
            s_f[r][kk] = fused[(size_t)(row0 + r) * CC + k0 + kk];
        }
        __syncthreads();
        for (int kk = 0; kk < 64; ++kk) {
            const float wv = w_out[(size_t)(k0 + kk) * CC + col];
            #pragma unroll
            for (int r = 0; r < ROWS; ++r) acc[r] += s_f[r][kk] * wv;
        }
    }
    const float bo = b_out[col];
    #pragma unroll
    for (int r = 0; r < ROWS; ++r) out[(size_t)(row0 + r) * CC + col] = acc[r] + bo;
}

extern "C" void kernel_launch(void* const* d_in, const int* in_sizes, int n_in,
                              void* d_out, int out_size, void* d_ws, size_t ws_size,
                              hipStream_t stream) {
    const float* query  = (const float*)d_in[0];
    const float* memory = (const float*)d_in[1];
    const float* refpts = (const float*)d_in[2];
    const float* w_off  = (const float*)d_in[3];
    const float* b_off  = (const float*)d_in[4];
    const float* w_wt   = (const float*)d_in[5];
    const float* b_wt   = (const float*)d_in[6];
    const float* w_out  = (const float*)d_in[7];
    const float* b_out  = (const float*)d_in[8];
    // d_in[9], d_in[10] = bev_h, bev_w (compile-time constants 200x200)

    float* fused = (float*)d_ws;                 // [B*N, C] f32 = 7.37 MB
    float* out   = (float*)d_out;

    deform_sample_kernel<<<BB * NN, 256, 0, stream>>>(
        query, memory, refpts, w_off, b_off, w_wt, b_wt, fused);
    out_gemm_kernel<<<(BB * NN) / ROWS, 256, 0, stream>>>(
        fused, w_out, b_out, out);
}

// Round 2
// 62.798 us; speedup vs baseline: 1.5700x; 1.5700x over previous
//
#include <hip/hip_runtime.h>
#include <math.h>

#define BB 8
#define NN 900
#define CC 256
#define HEADS 8
#define PP 4
#define BEV_H 200
#define BEV_W 200
#define HW (BEV_H * BEV_W)
#define HD 32
#define RADIUS 0.2f
#define M_TOT (BB * NN)      // 7200

// ---------------- Kernel A: projection GEMM + transform -> sampling records ----------------
// 16 rows per block, 256 threads: colid = t&31 (cols colid, +32, +64), rgrp = t>>5 (2 rows each)
#define AR 16
__global__ __launch_bounds__(256) void proj_kernel(
    const float* __restrict__ query,     // [M, 256]
    const float* __restrict__ refpts,    // [M, 2]
    const float* __restrict__ w_off,     // [256, 64]
    const float* __restrict__ b_off,     // [64]
    const float* __restrict__ w_wt,      // [256, 32]
    const float* __restrict__ b_wt,      // [32]
    float* __restrict__ rec_w,           // [M*32*4] corner weights
    int*   __restrict__ rec_i)           // [M*32*4] corner flat indices
{
    __shared__ float s_q[AR][64];        // 4 KB
    __shared__ float s_wc[64][96];       // 24 KB  (cols 0-63: w_off, 64-95: w_wt)
    __shared__ float s_l[AR][96];        // 6 KB logits

    const int t = threadIdx.x;
    const int row0 = blockIdx.x * AR;
    const int colid = t & 31;
    const int rbase = (t >> 5) * 2;      // rows rbase, rbase+1

    float acc[2][3] = {};

    for (int k0 = 0; k0 < CC; k0 += 64) {
        __syncthreads();
        // stage q tile: 16x64 = 256 float4, one per thread
        {
            const int word = t * 4;
            const int r = word >> 6, kk = word & 63;
            *(float4*)&s_q[r][kk] =
                *(const float4*)&query[(size_t)(row0 + r) * CC + k0 + kk];
        }
        // stage w_off chunk: 64x64 = 1024 float4, 4 per thread
        #pragma unroll
        for (int j = 0; j < 4; ++j) {
            const int word = (t + j * 256) * 4;
            const int kk = word >> 6, c = word & 63;
            *(float4*)&s_wc[kk][c] =
                *(const float4*)&w_off[(size_t)(k0 + kk) * 64 + c];
        }
        // stage w_wt chunk: 64x32 = 512 float4, 2 per thread
        #pragma unroll
        for (int j = 0; j < 2; ++j) {
            const int word = (t + j * 256) * 4;
            const int kk = word >> 5, c = word & 31;
            *(float4*)&s_wc[kk][64 + c] =
                *(const float4*)&w_wt[(size_t)(k0 + kk) * 32 + c];
        }
        __syncthreads();
        #pragma unroll 8
        for (int kk = 0; kk < 64; ++kk) {
            const float q0 = s_q[rbase + 0][kk];
            const float q1 = s_q[rbase + 1][kk];
            const float w0 = s_wc[kk][colid];
            const float w1 = s_wc[kk][colid + 32];
            const float w2 = s_wc[kk][colid + 64];
            acc[0][0] += q0 * w0; acc[0][1] += q0 * w1; acc[0][2] += q0 * w2;
            acc[1][0] += q1 * w0; acc[1][1] += q1 * w1; acc[1][2] += q1 * w2;
        }
    }

    // logits (+bias) -> LDS
    const float bo0 = b_off[colid];
    const float bo1 = b_off[colid + 32];
    const float bw  = b_wt[colid];
    s_l[rbase + 0][colid]      = acc[0][0] + bo0;
    s_l[rbase + 0][colid + 32] = acc[0][1] + bo1;
    s_l[rbase + 0][colid + 64] = acc[0][2] + bw;
    s_l[rbase + 1][colid]      = acc[1][0] + bo0;
    s_l[rbase + 1][colid + 32] = acc[1][1] + bo1;
    s_l[rbase + 1][colid + 64] = acc[1][2] + bw;
    __syncthreads();

    // transform: 128 threads = 16 rows x 8 heads
    if (t < AR * HEADS) {
        const int r = t >> 3, h = t & 7;
        const int bn = row0 + r;
        const float rx = refpts[(size_t)bn * 2 + 0];
        const float ry = refpts[(size_t)bn * 2 + 1];

        const float l0 = s_l[r][64 + h * 4 + 0];
        const float l1 = s_l[r][64 + h * 4 + 1];
        const float l2 = s_l[r][64 + h * 4 + 2];
        const float l3 = s_l[r][64 + h * 4 + 3];
        const float m = fmaxf(fmaxf(l0, l1), fmaxf(l2, l3));
        float e[PP];
        e[0] = expf(l0 - m); e[1] = expf(l1 - m);
        e[2] = expf(l2 - m); e[3] = expf(l3 - m);
        const float inv = 1.f / (e[0] + e[1] + e[2] + e[3]);

        #pragma unroll
        for (int p = 0; p < PP; ++p) {
            const float wt = e[p] * inv;
            const float ox = tanhf(s_l[r][h * 8 + p * 2 + 0]) * RADIUS;
            const float oy = tanhf(s_l[r][h * 8 + p * 2 + 1]) * RADIUS;
            const float x = (rx + ox) * (float)BEV_W - 0.5f;
            const float y = (ry + oy) * (float)BEV_H - 0.5f;
            const float x0f = floorf(x), y0f = floorf(y);
            const int x0 = (int)x0f, y0 = (int)y0f;
            const float fx = x - x0f, fy = y - y0f;
            const bool xv0 = (unsigned)x0 < (unsigned)BEV_W;
            const bool xv1 = (unsigned)(x0 + 1) < (unsigned)BEV_W;
            const bool yv0 = (unsigned)y0 < (unsigned)BEV_H;
            const bool yv1 = (unsigned)(y0 + 1) < (unsigned)BEV_H;
            const int cx0 = min(max(x0, 0), BEV_W - 1);
            const int cx1 = min(max(x0 + 1, 0), BEV_W - 1);
            const int cy0 = min(max(y0, 0), BEV_H - 1);
            const int cy1 = min(max(y0 + 1, 0), BEV_H - 1);
            float4 wv;
            wv.x = (xv0 && yv0) ? wt * (1.f - fx) * (1.f - fy) : 0.f;
            wv.y = (xv1 && yv0) ? wt * fx * (1.f - fy) : 0.f;
            wv.z = (xv0 && yv1) ? wt * (1.f - fx) * fy : 0.f;
            wv.w = (xv1 && yv1) ? wt * fx * fy : 0.f;
            int4 iv;
            iv.x = cy0 * BEV_W + cx0; iv.y = cy0 * BEV_W + cx1;
            iv.z = cy1 * BEV_W + cx0; iv.w = cy1 * BEV_W + cx1;
            ((float4*)rec_w)[(size_t)bn * 32 + h * 4 + p] = wv;
            ((int4*)rec_i)[(size_t)bn * 32 + h * 4 + p] = iv;
        }
    }
}

// ---------------- Kernel B: pure bilinear gather ----------------
__global__ __launch_bounds__(256) void sample_kernel(
    const float* __restrict__ memory,    // [B, HW, 256]
    const float* __restrict__ rec_w,
    const int*   __restrict__ rec_i,
    float* __restrict__ fused)           // [M, 256]
{
    const int bn = blockIdx.x;
    const int b = bn / NN;
    const int t = threadIdx.x;

    __shared__ float s_w[128];
    __shared__ int   s_i[128];
    if (t < 128) s_w[t] = rec_w[(size_t)bn * 128 + t];
    else         s_i[t - 128] = rec_i[(size_t)bn * 128 + (t - 128)];
    __syncthreads();

    const int h = t >> 5, ch = t & 31;
    const float* mem_b = memory + (size_t)b * HW * CC + h * HD + ch;
    float acc = 0.f;
    #pragma unroll
    for (int p = 0; p < PP; ++p) {
        const int base = (h * PP + p) * 4;
        acc += s_w[base + 0] * mem_b[(size_t)s_i[base + 0] * CC];
        acc += s_w[base + 1] * mem_b[(size_t)s_i[base + 1] * CC];
        acc += s_w[base + 2] * mem_b[(size_t)s_i[base + 2] * CC];
        acc += s_w[base + 3] * mem_b[(size_t)s_i[base + 3] * CC];
    }
    fused[(size_t)bn * CC + t] = acc;
}

// ---------------- Kernel C: out = fused @ w_out + b_out ----------------
#define CR 16
__global__ __launch_bounds__(256) void out_gemm_kernel(
    const float* __restrict__ fused,   // [M, 256]
    const float* __restrict__ w_out,   // [256, 256]
    const float* __restrict__ b_out,   // [256]
    float* __restrict__ out)           // [M, 256]
{
    const int row0 = blockIdx.x * CR;
    const int t = threadIdx.x;
    const int c4 = (t & 63) * 4;
    const int rg = t >> 6;               // rows rg*4 .. rg*4+3

    __shared__ float s_f[CR][64];
    float acc[4][4] = {};

    for (int k0 = 0; k0 < CC; k0 += 64) {
        __syncthreads();
        {
            const int word = t * 4;
            const int r = word >> 6, kk = word & 63;
            *(float4*)&s_f[r][kk] =
                *(const float4*)&fused[(size_t)(row0 + r) * CC + k0 + kk];
        }
        __syncthreads();
        #pragma unroll 8
        for (int kk = 0; kk < 64; ++kk) {
            const float4 wv = *(const float4*)&w_out[(size_t)(k0 + kk) * CC + c4];
            #pragma unroll
            for (int r = 0; r < 4; ++r) {
                const float fv = s_f[rg * 4 + r][kk];
                acc[r][0] += fv * wv.x;
                acc[r][1] += fv * wv.y;
                acc[r][2] += fv * wv.z;
                acc[r][3] += fv * wv.w;
            }
        }
    }
    const float4 bo = *(const float4*)&b_out[c4];
    #pragma unroll
    for (int r = 0; r < 4; ++r) {
        float4 o;
        o.x = acc[r][0] + bo.x; o.y = acc[r][1] + bo.y;
        o.z = acc[r][2] + bo.z; o.w = acc[r][3] + bo.w;
        *(float4*)&out[(size_t)(row0 + rg * 4 + r) * CC + c4] = o;
    }
}

extern "C" void kernel_launch(void* const* d_in, const int* in_sizes, int n_in,
                              void* d_out, int out_size, void* d_ws, size_t ws_size,
                              hipStream_t stream) {
    const float* query  = (const float*)d_in[0];
    const float* memory = (const float*)d_in[1];
    const float* refpts = (const float*)d_in[2];
    const float* w_off  = (const float*)d_in[3];
    const float* b_off  = (const float*)d_in[4];
    const float* w_wt   = (const float*)d_in[5];
    const float* b_wt   = (const float*)d_in[6];
    const float* w_out  = (const float*)d_in[7];
    const float* b_out  = (const float*)d_in[8];

    float* fused = (float*)d_ws;                         // 7200*256 f32
    float* rec_w = fused + (size_t)M_TOT * CC;           // 7200*128 f32
    int*   rec_i = (int*)(rec_w + (size_t)M_TOT * 128);  // 7200*128 i32
    float* out   = (float*)d_out;

    proj_kernel<<<M_TOT / AR, 256, 0, stream>>>(
        query, refpts, w_off, b_off, w_wt, b_wt, rec_w, rec_i);
    sample_kernel<<<M_TOT, 256, 0, stream>>>(memory, rec_w, rec_i, fused);
    out_gemm_kernel<<<M_TOT / CR, 256, 0, stream>>>(fused, w_out, b_out, out);
}

// Round 3
// 55.013 us; speedup vs baseline: 1.7921x; 1.1415x over previous
//
#include <hip/hip_runtime.h>
#include <math.h>

#define BB 8
#define NN 900
#define CC 256
#define HEADS 8
#define PP 4
#define BEV_H 200
#define BEV_W 200
#define HW (BEV_H * BEV_W)
#define HD 32
#define RADIUS 0.2f
#define M_TOT (BB * NN)      // 7200

typedef short s16x8 __attribute__((ext_vector_type(8)));
typedef float f32x4 __attribute__((ext_vector_type(4)));

static __device__ __forceinline__ unsigned short f2bf(float f) {
    unsigned int x = __float_as_uint(f);
    unsigned int r = x + 0x7FFFu + ((x >> 16) & 1u);   // RNE
    return (unsigned short)(r >> 16);
}

// ---------------- Kernel 0: pack w_out -> bf16 B-fragment layout ----------------
// Bp[kg*256 + n] is a 16B record of 8 bf16: w_out[kg*8 + j][n], j=0..7   (kg = 0..31)
__global__ __launch_bounds__(256) void pack_wout_kernel(
    const float* __restrict__ w_out, unsigned short* __restrict__ Bp)
{
    const int g = blockIdx.x * 256 + threadIdx.x;   // 0..8191
    const int n = g & 255;
    const int kg = g >> 8;                          // 0..31
    unsigned int w[4];
    #pragma unroll
    for (int jj = 0; jj < 4; ++jj) {
        const unsigned int lo = f2bf(w_out[(size_t)(kg * 8 + jj * 2 + 0) * CC + n]);
        const unsigned int hi = f2bf(w_out[(size_t)(kg * 8 + jj * 2 + 1) * CC + n]);
        w[jj] = lo | (hi << 16);
    }
    uint4 v; v.x = w[0]; v.y = w[1]; v.z = w[2]; v.w = w[3];
    *(uint4*)&Bp[(size_t)g * 8] = v;
}

// ---------------- Kernel A: projection GEMM + transform -> sampling records ----------------
#define AR 16
__global__ __launch_bounds__(256) void proj_kernel(
    const float* __restrict__ query,     // [M, 256]
    const float* __restrict__ refpts,    // [M, 2]
    const float* __restrict__ w_off,     // [256, 64]
    const float* __restrict__ b_off,     // [64]
    const float* __restrict__ w_wt,      // [256, 32]
    const float* __restrict__ b_wt,      // [32]
    float* __restrict__ rec_w,           // [M*32*4] corner weights
    int*   __restrict__ rec_i)           // [M*32*4] corner flat indices
{
    __shared__ float s_q[AR][64];
    __shared__ float s_wc[64][96];
    __shared__ float s_l[AR][96];

    const int t = threadIdx.x;
    const int row0 = blockIdx.x * AR;
    const int colid = t & 31;
    const int rbase = (t >> 5) * 2;

    float acc[2][3] = {};

    for (int k0 = 0; k0 < CC; k0 += 64) {
        __syncthreads();
        {
            const int word = t * 4;
            const int r = word >> 6, kk = word & 63;
            *(float4*)&s_q[r][kk] =
                *(const float4*)&query[(size_t)(row0 + r) * CC + k0 + kk];
        }
        #pragma unroll
        for (int j = 0; j < 4; ++j) {
            const int word = (t + j * 256) * 4;
            const int kk = word >> 6, c = word & 63;
            *(float4*)&s_wc[kk][c] =
                *(const float4*)&w_off[(size_t)(k0 + kk) * 64 + c];
        }
        #pragma unroll
        for (int j = 0; j < 2; ++j) {
            const int word = (t + j * 256) * 4;
            const int kk = word >> 5, c = word & 31;
            *(float4*)&s_wc[kk][64 + c] =
                *(const float4*)&w_wt[(size_t)(k0 + kk) * 32 + c];
        }
        __syncthreads();
        #pragma unroll 8
        for (int kk = 0; kk < 64; ++kk) {
            const float q0 = s_q[rbase + 0][kk];
            const float q1 = s_q[rbase + 1][kk];
            const float w0 = s_wc[kk][colid];
            const float w1 = s_wc[kk][colid + 32];
            const float w2 = s_wc[kk][colid + 64];
            acc[0][0] += q0 * w0; acc[0][1] += q0 * w1; acc[0][2] += q0 * w2;
            acc[1][0] += q1 * w0; acc[1][1] += q1 * w1; acc[1][2] += q1 * w2;
        }
    }

    const float bo0 = b_off[colid];
    const float bo1 = b_off[colid + 32];
    const float bw  = b_wt[colid];
    s_l[rbase + 0][colid]      = acc[0][0] + bo0;
    s_l[rbase + 0][colid + 32] = acc[0][1] + bo1;
    s_l[rbase + 0][colid + 64] = acc[0][2] + bw;
    s_l[rbase + 1][colid]      = acc[1][0] + bo0;
    s_l[rbase + 1][colid + 32] = acc[1][1] + bo1;
    s_l[rbase + 1][colid + 64] = acc[1][2] + bw;
    __syncthreads();

    if (t < AR * HEADS) {
        const int r = t >> 3, h = t & 7;
        const int bn = row0 + r;
        const float rx = refpts[(size_t)bn * 2 + 0];
        const float ry = refpts[(size_t)bn * 2 + 1];

        const float l0 = s_l[r][64 + h * 4 + 0];
        const float l1 = s_l[r][64 + h * 4 + 1];
        const float l2 = s_l[r][64 + h * 4 + 2];
        const float l3 = s_l[r][64 + h * 4 + 3];
        const float m = fmaxf(fmaxf(l0, l1), fmaxf(l2, l3));
        float e[PP];
        e[0] = expf(l0 - m); e[1] = expf(l1 - m);
        e[2] = expf(l2 - m); e[3] = expf(l3 - m);
        const float inv = 1.f / (e[0] + e[1] + e[2] + e[3]);

        #pragma unroll
        for (int p = 0; p < PP; ++p) {
            const float wt = e[p] * inv;
            const float ox = tanhf(s_l[r][h * 8 + p * 2 + 0]) * RADIUS;
            const float oy = tanhf(s_l[r][h * 8 + p * 2 + 1]) * RADIUS;
            const float x = (rx + ox) * (float)BEV_W - 0.5f;
            const float y = (ry + oy) * (float)BEV_H - 0.5f;
            const float x0f = floorf(x), y0f = floorf(y);
            const int x0 = (int)x0f, y0 = (int)y0f;
            const float fx = x - x0f, fy = y - y0f;
            const bool xv0 = (unsigned)x0 < (unsigned)BEV_W;
            const bool xv1 = (unsigned)(x0 + 1) < (unsigned)BEV_W;
            const bool yv0 = (unsigned)y0 < (unsigned)BEV_H;
            const bool yv1 = (unsigned)(y0 + 1) < (unsigned)BEV_H;
            const int cx0 = min(max(x0, 0), BEV_W - 1);
            const int cx1 = min(max(x0 + 1, 0), BEV_W - 1);
            const int cy0 = min(max(y0, 0), BEV_H - 1);
            const int cy1 = min(max(y0 + 1, 0), BEV_H - 1);
            float4 wv;
            wv.x = (xv0 && yv0) ? wt * (1.f - fx) * (1.f - fy) : 0.f;
            wv.y = (xv1 && yv0) ? wt * fx * (1.f - fy) : 0.f;
            wv.z = (xv0 && yv1) ? wt * (1.f - fx) * fy : 0.f;
            wv.w = (xv1 && yv1) ? wt * fx * fy : 0.f;
            int4 iv;
            iv.x = cy0 * BEV_W + cx0; iv.y = cy0 * BEV_W + cx1;
            iv.z = cy1 * BEV_W + cx0; iv.w = cy1 * BEV_W + cx1;
            ((float4*)rec_w)[(size_t)bn * 32 + h * 4 + p] = wv;
            ((int4*)rec_i)[(size_t)bn * 32 + h * 4 + p] = iv;
        }
    }
}

// ---------------- Kernel B: bilinear gather, float4 per lane, 4 queries/block ----------------
__global__ __launch_bounds__(256) void sample_kernel(
    const float* __restrict__ memory,    // [B, HW, 256]
    const float* __restrict__ rec_w,
    const int*   __restrict__ rec_i,
    unsigned short* __restrict__ fused)  // [M, 256] bf16
{
    const int q0 = blockIdx.x * 4;
    const int t = threadIdx.x;

    __shared__ float s_w[512];
    __shared__ int   s_i[512];
    #pragma unroll
    for (int j = 0; j < 2; ++j) {
        s_w[t + j * 256] = rec_w[(size_t)q0 * 128 + t + j * 256];
        s_i[t + j * 256] = rec_i[(size_t)q0 * 128 + t + j * 256];
    }
    __syncthreads();

    const int qi = t >> 6, lane = t & 63;
    const int q = q0 + qi;
    const int b = q / NN;
    const int h = lane >> 3;
    const int c4 = (lane & 7) * 4;

    const float* mb = memory + (size_t)b * HW * CC + h * HD + c4;
    const int rbase = qi * 128 + h * 16;

    float ax = 0.f, ay = 0.f, az = 0.f, aw = 0.f;
    #pragma unroll
    for (int j = 0; j < 16; ++j) {
        const float w = s_w[rbase + j];
        const int idx = s_i[rbase + j];
        const float4 v = *(const float4*)(mb + (size_t)idx * CC);
        ax += w * v.x; ay += w * v.y; az += w * v.z; aw += w * v.w;
    }
    ushort4 o;
    o.x = f2bf(ax); o.y = f2bf(ay); o.z = f2bf(az); o.w = f2bf(aw);
    *(ushort4*)&fused[(size_t)q * CC + h * HD + c4] = o;
}

// ---------------- Kernel C: out = fused(bf16) @ w_out(bf16,packed) + b_out  via MFMA ----------------
// grid (225, 2), 256 threads = 4 waves. Block: 32 M-rows, 128 N-cols (wave: 32x32).
__global__ __launch_bounds__(256) void mfma_gemm_kernel(
    const unsigned short* __restrict__ A,   // fused bf16 [M,256]
    const unsigned short* __restrict__ Bp,  // packed w_out bf16
    const float* __restrict__ b_out,
    float* __restrict__ out)                // [M,256] f32
{
    const int t = threadIdx.x;
    const int lane = t & 63, wid = t >> 6;
    const int m0 = blockIdx.x * 32;
    const int n0 = blockIdx.y * 128 + wid * 32;
    const int lr = lane & 15;      // row within A-frag / col within B,D frags
    const int lg = lane >> 4;      // k-group

    f32x4 acc[2][2] = {};

    const unsigned short* Ab = A + ((size_t)(m0 + lr) * CC + lg * 8);
    const unsigned short* Bb = Bp + ((size_t)lg * 256 + n0 + lr) * 8;

    #pragma unroll
    for (int ks = 0; ks < 8; ++ks) {
        const s16x8 a0 = *(const s16x8*)(Ab + ks * 32);
        const s16x8 a1 = *(const s16x8*)(Ab + ks * 32 + 16 * CC);
        const s16x8 b0 = *(const s16x8*)(Bb + (size_t)(ks * 1024) * 8);
        const s16x8 b1 = *(const s16x8*)(Bb + (size_t)(ks * 1024 + 16) * 8);
        acc[0][0] = __builtin_amdgcn_mfma_f32_16x16x32_bf16(a0, b0, acc[0][0], 0, 0, 0);
        acc[0][1] = __builtin_amdgcn_mfma_f32_16x16x32_bf16(a0, b1, acc[0][1], 0, 0, 0);
        acc[1][0] = __builtin_amdgcn_mfma_f32_16x16x32_bf16(a1, b0, acc[1][0], 0, 0, 0);
        acc[1][1] = __builtin_amdgcn_mfma_f32_16x16x32_bf16(a1, b1, acc[1][1], 0, 0, 0);
    }

    const int row_l = lg * 4;
    const float bo0 = b_out[n0 + lr];
    const float bo1 = b_out[n0 + 16 + lr];
    #pragma unroll
    for (int mt = 0; mt < 2; ++mt) {
        #pragma unroll
        for (int r = 0; r < 4; ++r) {
            const size_t row = (size_t)(m0 + mt * 16 + row_l + r) * CC;
            out[row + n0 + lr]      = acc[mt][0][r] + bo0;
            out[row + n0 + 16 + lr] = acc[mt][1][r] + bo1;
        }
    }
}

extern "C" void kernel_launch(void* const* d_in, const int* in_sizes, int n_in,
                              void* d_out, int out_size, void* d_ws, size_t ws_size,
                              hipStream_t stream) {
    const float* query  = (const float*)d_in[0];
    const float* memory = (const float*)d_in[1];
    const float* refpts = (const float*)d_in[2];
    const float* w_off  = (const float*)d_in[3];
    const float* b_off  = (const float*)d_in[4];
    const float* w_wt   = (const float*)d_in[5];
    const float* b_wt   = (const float*)d_in[6];
    const float* w_out  = (const float*)d_in[7];
    const float* b_out  = (const float*)d_in[8];

    char* ws = (char*)d_ws;
    float*          rec_w = (float*)(ws);                        // 921600 f32
    int*            rec_i = (int*)(ws + 3686400);                // 921600 i32
    unsigned short* fused = (unsigned short*)(ws + 7372800);     // 1843200 bf16
    unsigned short* wpack = (unsigned short*)(ws + 11059200);    // 65536 bf16
    float* out = (float*)d_out;

    pack_wout_kernel<<<32, 256, 0, stream>>>(w_out, wpack);
    proj_kernel<<<M_TOT / AR, 256, 0, stream>>>(
        query, refpts, w_off, b_off, w_wt, b_wt, rec_w, rec_i);
    sample_kernel<<<M_TOT / 4, 256, 0, stream>>>(memory, rec_w, rec_i, fused);
    dim3 ggrid(M_TOT / 32, 2);
    mfma_gemm_kernel<<<ggrid, 256, 0, stream>>>(fused, wpack, b_out, out);
}

// Round 4
// 43.379 us; speedup vs baseline: 2.2728x; 1.2682x over previous
//
#include <hip/hip_runtime.h>
#include <math.h>

#define BB 8
#define NN 900
#define CC 256
#define HEADS 8
#define PP 4
#define BEV_H 200
#define BEV_W 200
#define HW (BEV_H * BEV_W)
#define HD 32
#define RADIUS 0.2f
#define M_TOT (BB * NN)          // 7200

#define PROJ_AR 32
#define PROJ_BLOCKS (M_TOT / PROJ_AR)   // 225
#define PACK_BLOCKS 32
#define SR 16                    // queries per sample_gemm block
#define SFS 280                  // ushort stride of s_f rows (560 B, 16B-aligned, ~2-way banks)

typedef short s16x8 __attribute__((ext_vector_type(8)));
typedef float f32x4 __attribute__((ext_vector_type(4)));

static __device__ __forceinline__ unsigned short f2bf(float f) {
    unsigned int x = __float_as_uint(f);
    unsigned int r = x + 0x7FFFu + ((x >> 16) & 1u);   // RNE
    return (unsigned short)(r >> 16);
}

// ============ Kernel 1: projection GEMM + transform -> records, and w_out pack ============
__global__ __launch_bounds__(256) void proj_pack_kernel(
    const float* __restrict__ query,     // [M, 256]
    const float* __restrict__ refpts,    // [M, 2]
    const float* __restrict__ w_off,     // [256, 64]
    const float* __restrict__ b_off,     // [64]
    const float* __restrict__ w_wt,      // [256, 32]
    const float* __restrict__ b_wt,      // [32]
    const float* __restrict__ w_out,     // [256, 256]
    float* __restrict__ rec_w,           // [M*128] corner weights
    int*   __restrict__ rec_i,           // [M*128] corner indices
    unsigned short* __restrict__ Bp)     // packed w_out bf16
{
    const int t = threadIdx.x;

    // -------- pack branch: blocks 225..256 convert w_out to B-fragment records --------
    if (blockIdx.x >= PROJ_BLOCKS) {
        const int g = (blockIdx.x - PROJ_BLOCKS) * 256 + t;   // 0..8191
        const int n = g & 255, kg = g >> 8;                    // kg = k-group of 8
        unsigned int w[4];
        #pragma unroll
        for (int jj = 0; jj < 4; ++jj) {
            const unsigned int lo = f2bf(w_out[(size_t)(kg * 8 + jj * 2 + 0) * CC + n]);
            const unsigned int hi = f2bf(w_out[(size_t)(kg * 8 + jj * 2 + 1) * CC + n]);
            w[jj] = lo | (hi << 16);
        }
        uint4 v; v.x = w[0]; v.y = w[1]; v.z = w[2]; v.w = w[3];
        *(uint4*)&Bp[(size_t)g * 8] = v;
        return;
    }

    // -------- projection: 32 rows x 96 cols, thread = (row r, col-quad cq of 12 cols) --------
    __shared__ float s_q[PROJ_AR][68];    // +4 pad: q reads across 8 rows hit 8 banks
    __shared__ float s_w[64][96];         // row-major; inner reads are broadcast b128
    __shared__ float s_l[PROJ_AR][100];   // logits, +4 pad

    const int row0 = blockIdx.x * PROJ_AR;
    const int r  = t >> 3;               // 0..31
    const int cq = t & 7;                // cols cq*12 .. cq*12+11

    float acc[12] = {};

    for (int k0 = 0; k0 < CC; k0 += 64) {
        __syncthreads();
        // stage q tile 32x64 (512 float4, 2/thread)
        #pragma unroll
        for (int j = 0; j < 2; ++j) {
            const int e = (t + j * 256) * 4;
            const int rr = e >> 6, kk = e & 63;
            *(float4*)&s_q[rr][kk] =
                *(const float4*)&query[(size_t)(row0 + rr) * CC + k0 + kk];
        }
        // stage w_off tile 64x64 (1024 float4, 4/thread), row-major
        #pragma unroll
        for (int j = 0; j < 4; ++j) {
            const int e = t + j * 256;
            const int kk = e >> 4, c4 = (e & 15) * 4;
            *(float4*)&s_w[kk][c4] =
                *(const float4*)&w_off[(size_t)(k0 + kk) * 64 + c4];
        }
        // stage w_wt tile 64x32 (512 float4, 2/thread) into cols 64..95
        #pragma unroll
        for (int j = 0; j < 2; ++j) {
            const int e = t + j * 256;
            const int kk = e >> 3, c4 = (e & 7) * 4;
            *(float4*)&s_w[kk][64 + c4] =
                *(const float4*)&w_wt[(size_t)(k0 + kk) * 32 + c4];
        }
        __syncthreads();
        #pragma unroll 8
        for (int kk = 0; kk < 64; ++kk) {
            const float qv = s_q[r][kk];
            const float4 w0 = *(const float4*)&s_w[kk][cq * 12 + 0];
            const float4 w1 = *(const float4*)&s_w[kk][cq * 12 + 4];
            const float4 w2 = *(const float4*)&s_w[kk][cq * 12 + 8];
            acc[0]  += qv * w0.x; acc[1]  += qv * w0.y;
            acc[2]  += qv * w0.z; acc[3]  += qv * w0.w;
            acc[4]  += qv * w1.x; acc[5]  += qv * w1.y;
            acc[6]  += qv * w1.z; acc[7]  += qv * w1.w;
            acc[8]  += qv * w2.x; acc[9]  += qv * w2.y;
            acc[10] += qv * w2.z; acc[11] += qv * w2.w;
        }
    }

    // bias + logits to LDS
    #pragma unroll
    for (int j = 0; j < 12; ++j) {
        const int col = cq * 12 + j;
        const float bias = (col < 64) ? b_off[col] : b_wt[col - 64];
        s_l[r][col] = acc[j] + bias;
    }
    __syncthreads();

    // -------- transform: 256 threads = 32 rows x 8 heads --------
    {
        const int h = t & 7;             // r = t>>3 (same as above)
        const int bn = row0 + r;
        const float rx = refpts[(size_t)bn * 2 + 0];
        const float ry = refpts[(size_t)bn * 2 + 1];

        const float l0 = s_l[r][64 + h * 4 + 0];
        const float l1 = s_l[r][64 + h * 4 + 1];
        const float l2 = s_l[r][64 + h * 4 + 2];
        const float l3 = s_l[r][64 + h * 4 + 3];
        const float m = fmaxf(fmaxf(l0, l1), fmaxf(l2, l3));
        float e0 = expf(l0 - m), e1 = expf(l1 - m), e2 = expf(l2 - m), e3 = expf(l3 - m);
        const float inv = 1.f / (e0 + e1 + e2 + e3);
        float ww[4] = {e0 * inv, e1 * inv, e2 * inv, e3 * inv};

        #pragma unroll
        for (int p = 0; p < PP; ++p) {
            const float wt = ww[p];
            const float ox = tanhf(s_l[r][h * 8 + p * 2 + 0]) * RADIUS;
            const float oy = tanhf(s_l[r][h * 8 + p * 2 + 1]) * RADIUS;
            const float x = (rx + ox) * (float)BEV_W - 0.5f;
            const float y = (ry + oy) * (float)BEV_H - 0.5f;
            const float x0f = floorf(x), y0f = floorf(y);
            const int x0 = (int)x0f, y0 = (int)y0f;
            const float fx = x - x0f, fy = y - y0f;
            const bool xv0 = (unsigned)x0 < (unsigned)BEV_W;
            const bool xv1 = (unsigned)(x0 + 1) < (unsigned)BEV_W;
            const bool yv0 = (unsigned)y0 < (unsigned)BEV_H;
            const bool yv1 = (unsigned)(y0 + 1) < (unsigned)BEV_H;
            const int cx0 = min(max(x0, 0), BEV_W - 1);
            const int cx1 = min(max(x0 + 1, 0), BEV_W - 1);
            const int cy0 = min(max(y0, 0), BEV_H - 1);
            const int cy1 = min(max(y0 + 1, 0), BEV_H - 1);
            float4 wv;
            wv.x = (xv0 && yv0) ? wt * (1.f - fx) * (1.f - fy) : 0.f;
            wv.y = (xv1 && yv0) ? wt * fx * (1.f - fy) : 0.f;
            wv.z = (xv0 && yv1) ? wt * (1.f - fx) * fy : 0.f;
            wv.w = (xv1 && yv1) ? wt * fx * fy : 0.f;
            int4 iv;
            iv.x = cy0 * BEV_W + cx0; iv.y = cy0 * BEV_W + cx1;
            iv.z = cy1 * BEV_W + cx0; iv.w = cy1 * BEV_W + cx1;
            ((float4*)rec_w)[(size_t)bn * 32 + h * 4 + p] = wv;
            ((int4*)rec_i)[(size_t)bn * 32 + h * 4 + p] = iv;
        }
    }
}

// ============ Kernel 2: gather -> bf16 LDS tile -> MFMA out-projection ============
__global__ __launch_bounds__(256, 2) void sample_gemm_kernel(
    const float* __restrict__ memory,    // [B, HW, 256]
    const float* __restrict__ rec_w,
    const int*   __restrict__ rec_i,
    const unsigned short* __restrict__ Bp,
    const float* __restrict__ b_out,
    float* __restrict__ out)             // [M, 256] f32
{
    const int t = threadIdx.x;
    const int bn0 = blockIdx.x * SR;

    __shared__ float s_w[SR][128];
    __shared__ int   s_i[SR][128];
    __shared__ unsigned short s_f[SR * SFS];

    // stage records, transposed: global [q][h*16+jj] -> LDS [q][jj*8+h] (conflict-free reads)
    #pragma unroll
    for (int j = 0; j < 2; ++j) {
        const int e4 = (t + j * 256) * 4;          // 0..2044, q=e4>>7, h=(e4>>4)&7, j0=e4&15
        const int q = e4 >> 7;
        const int h = (e4 >> 4) & 7;
        const int j0 = e4 & 15;
        const float4 wv = *(const float4*)&rec_w[(size_t)bn0 * 128 + e4];
        const int4   iv = *(const int4*)&rec_i[(size_t)bn0 * 128 + e4];
        s_w[q][(j0 + 0) * 8 + h] = wv.x; s_i[q][(j0 + 0) * 8 + h] = iv.x;
        s_w[q][(j0 + 1) * 8 + h] = wv.y; s_i[q][(j0 + 1) * 8 + h] = iv.y;
        s_w[q][(j0 + 2) * 8 + h] = wv.z; s_i[q][(j0 + 2) * 8 + h] = iv.z;
        s_w[q][(j0 + 3) * 8 + h] = wv.w; s_i[q][(j0 + 3) * 8 + h] = iv.w;
    }
    __syncthreads();

    // gather: thread = (qg, h, l8); 4 queries x 16 weighted float4 loads each
    {
        const int qg = t >> 6, h = (t >> 3) & 7, l8 = t & 7;
        const int coff = h * HD + l8 * 4;          // channel offset
        #pragma unroll
        for (int i = 0; i < 4; ++i) {
            const int ql = qg * 4 + i;
            const int bn = bn0 + ql;
            const int b = bn / NN;
            const float* mb = memory + (size_t)b * HW * CC + coff;
            float ax = 0.f, ay = 0.f, az = 0.f, aw = 0.f;
            #pragma unroll
            for (int j = 0; j < 16; ++j) {
                const float w = s_w[ql][j * 8 + h];
                const int idx = s_i[ql][j * 8 + h];
                const float4 v = *(const float4*)(mb + (size_t)idx * CC);
                ax += w * v.x; ay += w * v.y; az += w * v.z; aw += w * v.w;
            }
            ushort4 o; o.x = f2bf(ax); o.y = f2bf(ay); o.z = f2bf(az); o.w = f2bf(aw);
            *(ushort4*)&s_f[ql * SFS + coff] = o;
        }
    }
    __syncthreads();

    // MFMA: 4 waves, wave wid covers cols wid*64..+63; M=16 rows = this block's queries
    {
        const int lane = t & 63, wid = t >> 6;
        const int lr = lane & 15, lg = lane >> 4;
        const int n0w = wid * 64;
        f32x4 acc[4] = {};
        const unsigned short* Bb = Bp + ((size_t)lg * 256 + n0w + lr) * 8;
        const unsigned short* Ar = &s_f[lr * SFS + lg * 8];
        #pragma unroll
        for (int ks = 0; ks < 8; ++ks) {
            const s16x8 a = *(const s16x8*)(Ar + ks * 32);
            #pragma unroll
            for (int nt = 0; nt < 4; ++nt) {
                const s16x8 bv = *(const s16x8*)(Bb + (size_t)(ks * 4 * 256 + nt * 16) * 8);
                acc[nt] = __builtin_amdgcn_mfma_f32_16x16x32_bf16(a, bv, acc[nt], 0, 0, 0);
            }
        }
        #pragma unroll
        for (int nt = 0; nt < 4; ++nt) {
            const float bo = b_out[n0w + nt * 16 + lr];
            #pragma unroll
            for (int rr = 0; rr < 4; ++rr) {
                out[(size_t)(bn0 + lg * 4 + rr) * CC + n0w + nt * 16 + lr] = acc[nt][rr] + bo;
            }
        }
    }
}

extern "C" void kernel_launch(void* const* d_in, const int* in_sizes, int n_in,
                              void* d_out, int out_size, void* d_ws, size_t ws_size,
                              hipStream_t stream) {
    const float* query  = (const float*)d_in[0];
    const float* memory = (const float*)d_in[1];
    const float* refpts = (const float*)d_in[2];
    const float* w_off  = (const float*)d_in[3];
    const float* b_off  = (const float*)d_in[4];
    const float* w_wt   = (const float*)d_in[5];
    const float* b_wt   = (const float*)d_in[6];
    const float* w_out  = (const float*)d_in[7];
    const float* b_out  = (const float*)d_in[8];

    char* ws = (char*)d_ws;
    float*          rec_w = (float*)(ws);                     // M*128 f32 = 3.69 MB
    int*            rec_i = (int*)(ws + 3686400);             // M*128 i32 = 3.69 MB
    unsigned short* Bp    = (unsigned short*)(ws + 7372800);  // 8192*8 bf16 = 128 KB
    float* out = (float*)d_out;

    proj_pack_kernel<<<PROJ_BLOCKS + PACK_BLOCKS, 256, 0, stream>>>(
        query, refpts, w_off, b_off, w_wt, b_wt, w_out, rec_w, rec_i, Bp);
    sample_gemm_kernel<<<M_TOT / SR, 256, 0, stream>>>(
        memory, rec_w, rec_i, Bp, b_out, out);
}

// Round 5
// 35.656 us; speedup vs baseline: 2.7650x; 1.2166x over previous
//
#include <hip/hip_runtime.h>
#include <math.h>

#define BB 8
#define NN 900
#define CC 256
#define HEADS 8
#define PP 4
#define BEV_H 200
#define BEV_W 200
#define HW (BEV_H * BEV_W)
#define HD 32
#define RADIUS 0.2f
#define M_TOT (BB * NN)          // 7200

#define SR 16                    // queries per fused block
#define QS 264                   // ushort stride of s_qhi/s_qlo rows
#define RS 132                   // float stride of record rows (pad vs 128)
#define SFS 280                  // ushort stride of s_f rows

typedef short s16x8 __attribute__((ext_vector_type(8)));
typedef float f32x4 __attribute__((ext_vector_type(4)));

static __device__ __forceinline__ unsigned short f2bf(float f) {
    unsigned int x = __float_as_uint(f);
    unsigned int r = x + 0x7FFFu + ((x >> 16) & 1u);   // RNE
    return (unsigned short)(r >> 16);
}
static __device__ __forceinline__ float bf2f(unsigned short h) {
    return __uint_as_float(((unsigned int)h) << 16);
}

// ============ Kernel 0: pack weights ============
// blocks 0..31 : Bp  (w_out  -> B-frag records, 32 kg x 256 n)
// blocks 32..43: Wp  (w_off|w_wt -> B-frag records hi/lo, 32 kg x 96 n)
__global__ __launch_bounds__(256) void pack_kernel(
    const float* __restrict__ w_off,   // [256,64]
    const float* __restrict__ w_wt,    // [256,32]
    const float* __restrict__ w_out,   // [256,256]
    unsigned short* __restrict__ Wp_hi,
    unsigned short* __restrict__ Wp_lo,
    unsigned short* __restrict__ Bp)
{
    const int t = threadIdx.x, blk = blockIdx.x;
    if (blk < 32) {
        const int g = blk * 256 + t;          // 0..8191
        const int n = g & 255, kg = g >> 8;
        unsigned int w[4];
        #pragma unroll
        for (int jj = 0; jj < 4; ++jj) {
            const unsigned int lo = f2bf(w_out[(size_t)(kg * 8 + jj * 2 + 0) * CC + n]);
            const unsigned int hi = f2bf(w_out[(size_t)(kg * 8 + jj * 2 + 1) * CC + n]);
            w[jj] = lo | (hi << 16);
        }
        uint4 v; v.x = w[0]; v.y = w[1]; v.z = w[2]; v.w = w[3];
        *(uint4*)&Bp[(size_t)g * 8] = v;
    } else {
        const int gid = (blk - 32) * 256 + t;  // 0..3071
        const int kg = gid / 96, n = gid - kg * 96;
        unsigned int wh[4], wl[4];
        #pragma unroll
        for (int jj = 0; jj < 4; ++jj) {
            unsigned int hp[2], lp[2];
            #pragma unroll
            for (int s = 0; s < 2; ++s) {
                const int k = kg * 8 + jj * 2 + s;
                const float w = (n < 64) ? w_off[(size_t)k * 64 + n]
                                         : w_wt[(size_t)k * 32 + (n - 64)];
                const unsigned short h = f2bf(w);
                hp[s] = h;
                lp[s] = f2bf(w - bf2f(h));
            }
            wh[jj] = hp[0] | (hp[1] << 16);
            wl[jj] = lp[0] | (lp[1] << 16);
        }
        uint4 vh; vh.x = wh[0]; vh.y = wh[1]; vh.z = wh[2]; vh.w = wh[3];
        uint4 vl; vl.x = wl[0]; vl.y = wl[1]; vl.z = wl[2]; vl.w = wl[3];
        *(uint4*)&Wp_hi[(size_t)gid * 8] = vh;
        *(uint4*)&Wp_lo[(size_t)gid * 8] = vl;
    }
}

// ============ Kernel 1: fused proj(bf16x3 MFMA) + transform + gather + out-MFMA ============
__global__ __launch_bounds__(256, 2) void fused_kernel(
    const float* __restrict__ query,     // [M,256]
    const float* __restrict__ refpts,    // [M,2]
    const float* __restrict__ memory,    // [B,HW,256]
    const float* __restrict__ b_off,     // [64]
    const float* __restrict__ b_wt,      // [32]
    const float* __restrict__ b_out,     // [256]
    const unsigned short* __restrict__ Wp_hi,
    const unsigned short* __restrict__ Wp_lo,
    const unsigned short* __restrict__ Bp,
    float* __restrict__ out)             // [M,256]
{
    const int t = threadIdx.x;
    const int bn0 = blockIdx.x * SR;
    const int lane = t & 63, wid = t >> 6;
    const int lr = lane & 15, lg = lane >> 4;

    __shared__ unsigned short s_qhi[SR * QS];
    __shared__ unsigned short s_qlo[SR * QS];
    __shared__ float s_l[SR][100];
    __shared__ float s_rw[SR * RS];
    __shared__ int   s_ri[SR * RS];
    __shared__ unsigned short s_f[SR * SFS];

    // ---- Phase A: load query rows, split into bf16 hi/lo ----
    #pragma unroll
    for (int j = 0; j < 4; ++j) {
        const int e4 = (t + j * 256) * 4;      // 0..4092
        const int r = e4 >> 8, c = e4 & 255;
        const float4 q = *(const float4*)&query[(size_t)(bn0 + r) * CC + c];
        ushort4 hv, lv;
        hv.x = f2bf(q.x); lv.x = f2bf(q.x - bf2f(hv.x));
        hv.y = f2bf(q.y); lv.y = f2bf(q.y - bf2f(hv.y));
        hv.z = f2bf(q.z); lv.z = f2bf(q.z - bf2f(hv.z));
        hv.w = f2bf(q.w); lv.w = f2bf(q.w - bf2f(hv.w));
        *(ushort4*)&s_qhi[r * QS + c] = hv;
        *(ushort4*)&s_qlo[r * QS + c] = lv;
    }
    __syncthreads();

    // ---- Phase B: proj GEMM via bf16x3 MFMA (waves 0..2, 2 n-tiles of 16 each) ----
    if (wid < 3) {
        f32x4 pa[2] = {};
        #pragma unroll
        for (int ks = 0; ks < 8; ++ks) {
            const s16x8 ahi = *(const s16x8*)&s_qhi[lr * QS + lg * 8 + ks * 32];
            const s16x8 alo = *(const s16x8*)&s_qlo[lr * QS + lg * 8 + ks * 32];
            #pragma unroll
            for (int n = 0; n < 2; ++n) {
                const int nt = wid * 2 + n;
                const size_t boff = ((size_t)(lg + ks * 4) * 96 + nt * 16 + lr) * 8;
                const s16x8 bhi = *(const s16x8*)&Wp_hi[boff];
                const s16x8 blo = *(const s16x8*)&Wp_lo[boff];
                pa[n] = __builtin_amdgcn_mfma_f32_16x16x32_bf16(ahi, bhi, pa[n], 0, 0, 0);
                pa[n] = __builtin_amdgcn_mfma_f32_16x16x32_bf16(ahi, blo, pa[n], 0, 0, 0);
                pa[n] = __builtin_amdgcn_mfma_f32_16x16x32_bf16(alo, bhi, pa[n], 0, 0, 0);
            }
        }
        #pragma unroll
        for (int n = 0; n < 2; ++n) {
            const int nt = wid * 2 + n;
            #pragma unroll
            for (int r = 0; r < 4; ++r)
                s_l[lg * 4 + r][nt * 16 + lr] = pa[n][r];
        }
    }
    __syncthreads();

    // ---- Phase C: transform (threads 0..127 = 16 rows x 8 heads) ----
    if (t < SR * HEADS) {
        const int r = t >> 3, h = t & 7;
        const int bn = bn0 + r;
        const float rx = refpts[(size_t)bn * 2 + 0];
        const float ry = refpts[(size_t)bn * 2 + 1];

        const float l0 = s_l[r][64 + h * 4 + 0] + b_wt[h * 4 + 0];
        const float l1 = s_l[r][64 + h * 4 + 1] + b_wt[h * 4 + 1];
        const float l2 = s_l[r][64 + h * 4 + 2] + b_wt[h * 4 + 2];
        const float l3 = s_l[r][64 + h * 4 + 3] + b_wt[h * 4 + 3];
        const float m = fmaxf(fmaxf(l0, l1), fmaxf(l2, l3));
        const float e0 = expf(l0 - m), e1 = expf(l1 - m);
        const float e2 = expf(l2 - m), e3 = expf(l3 - m);
        const float inv = 1.f / (e0 + e1 + e2 + e3);
        const float ww[4] = {e0 * inv, e1 * inv, e2 * inv, e3 * inv};

        #pragma unroll
        for (int p = 0; p < PP; ++p) {
            const float wt = ww[p];
            const float ox = tanhf(s_l[r][h * 8 + p * 2 + 0] + b_off[h * 8 + p * 2 + 0]) * RADIUS;
            const float oy = tanhf(s_l[r][h * 8 + p * 2 + 1] + b_off[h * 8 + p * 2 + 1]) * RADIUS;
            const float x = (rx + ox) * (float)BEV_W - 0.5f;
            const float y = (ry + oy) * (float)BEV_H - 0.5f;
            const float x0f = floorf(x), y0f = floorf(y);
            const int x0 = (int)x0f, y0 = (int)y0f;
            const float fx = x - x0f, fy = y - y0f;
            const bool xv0 = (unsigned)x0 < (unsigned)BEV_W;
            const bool xv1 = (unsigned)(x0 + 1) < (unsigned)BEV_W;
            const bool yv0 = (unsigned)y0 < (unsigned)BEV_H;
            const bool yv1 = (unsigned)(y0 + 1) < (unsigned)BEV_H;
            const int cx0 = min(max(x0, 0), BEV_W - 1);
            const int cx1 = min(max(x0 + 1, 0), BEV_W - 1);
            const int cy0 = min(max(y0, 0), BEV_H - 1);
            const int cy1 = min(max(y0 + 1, 0), BEV_H - 1);
            const int base = r * RS + p * 32 + h;    // (p*4+c)*8 + h, c=0..3
            s_rw[base + 0]  = (xv0 && yv0) ? wt * (1.f - fx) * (1.f - fy) : 0.f;
            s_rw[base + 8]  = (xv1 && yv0) ? wt * fx * (1.f - fy) : 0.f;
            s_rw[base + 16] = (xv0 && yv1) ? wt * (1.f - fx) * fy : 0.f;
            s_rw[base + 24] = (xv1 && yv1) ? wt * fx * fy : 0.f;
            s_ri[base + 0]  = cy0 * BEV_W + cx0;
            s_ri[base + 8]  = cy0 * BEV_W + cx1;
            s_ri[base + 16] = cy1 * BEV_W + cx0;
            s_ri[base + 24] = cy1 * BEV_W + cx1;
        }
    }
    __syncthreads();

    // ---- Phase D: bilinear gather into bf16 LDS tile ----
    {
        const int qg = t >> 6, h = (t >> 3) & 7, l8 = t & 7;
        const int coff = h * HD + l8 * 4;
        #pragma unroll
        for (int i = 0; i < 4; ++i) {
            const int ql = qg * 4 + i;
            const int bn = bn0 + ql;
            const int b = bn / NN;
            const float* mb = memory + (size_t)b * HW * CC + coff;
            float ax = 0.f, ay = 0.f, az = 0.f, aw = 0.f;
            #pragma unroll
            for (int j = 0; j < 16; ++j) {
                const float w = s_rw[ql * RS + j * 8 + h];
                const int idx = s_ri[ql * RS + j * 8 + h];
                const float4 v = *(const float4*)(mb + (size_t)idx * CC);
                ax += w * v.x; ay += w * v.y; az += w * v.z; aw += w * v.w;
            }
            ushort4 o; o.x = f2bf(ax); o.y = f2bf(ay); o.z = f2bf(az); o.w = f2bf(aw);
            *(ushort4*)&s_f[ql * SFS + coff] = o;
        }
    }
    __syncthreads();

    // ---- Phase E: out-projection MFMA (4 waves x 64 cols) ----
    {
        const int n0w = wid * 64;
        f32x4 acc[4] = {};
        const unsigned short* Bb = Bp + ((size_t)lg * 256 + n0w + lr) * 8;
        const unsigned short* Ar = &s_f[lr * SFS + lg * 8];
        #pragma unroll
        for (int ks = 0; ks < 8; ++ks) {
            const s16x8 a = *(const s16x8*)(Ar + ks * 32);
            #pragma unroll
            for (int nt = 0; nt < 4; ++nt) {
                const s16x8 bv = *(const s16x8*)(Bb + (size_t)(ks * 1024 + nt * 16) * 8);
                acc[nt] = __builtin_amdgcn_mfma_f32_16x16x32_bf16(a, bv, acc[nt], 0, 0, 0);
            }
        }
        #pragma unroll
        for (int nt = 0; nt < 4; ++nt) {
            const float bo = b_out[n0w + nt * 16 + lr];
            #pragma unroll
            for (int rr = 0; rr < 4; ++rr) {
                out[(size_t)(bn0 + lg * 4 + rr) * CC + n0w + nt * 16 + lr] = acc[nt][rr] + bo;
            }
        }
    }
}

extern "C" void kernel_launch(void* const* d_in, const int* in_sizes, int n_in,
                              void* d_out, int out_size, void* d_ws, size_t ws_size,
                              hipStream_t stream) {
    const float* query  = (const float*)d_in[0];
    const float* memory = (const float*)d_in[1];
    const float* refpts = (const float*)d_in[2];
    const float* w_off  = (const float*)d_in[3];
    const float* b_off  = (const float*)d_in[4];
    const float* w_wt   = (const float*)d_in[5];
    const float* b_wt   = (const float*)d_in[6];
    const float* w_out  = (const float*)d_in[7];
    const float* b_out  = (const float*)d_in[8];

    char* ws = (char*)d_ws;
    unsigned short* Bp    = (unsigned short*)(ws);            // 65536 bf16 = 128 KB
    unsigned short* Wp_hi = (unsigned short*)(ws + 131072);   // 24576 bf16 = 48 KB
    unsigned short* Wp_lo = (unsigned short*)(ws + 180224);   // 24576 bf16 = 48 KB
    float* out = (float*)d_out;

    pack_kernel<<<44, 256, 0, stream>>>(w_off, w_wt, w_out, Wp_hi, Wp_lo, Bp);
    fused_kernel<<<M_TOT / SR, 256, 0, stream>>>(
        query, refpts, memory, b_off, b_wt, b_out, Wp_hi, Wp_lo, Bp, out);
}

// Round 6
// 35.537 us; speedup vs baseline: 2.7743x; 1.0033x over previous
//
#include <hip/hip_runtime.h>
#include <math.h>

#define BB 8
#define NN 900
#define CC 256
#define HEADS 8
#define PP 4
#define BEV_H 200
#define BEV_W 200
#define HW (BEV_H * BEV_W)
#define HD 32
#define RADIUS 0.2f
#define M_TOT (BB * NN)          // 7200

#define SR 16                    // queries per fused block
#define QS 264                   // ushort stride of s_qhi/s_qlo rows
#define RS 132                   // element stride of record rows
#define SFS 280                  // ushort stride of s_f rows

// shared-memory layout (bytes), phase-aliased:
//   [0      .. 8447 ]  s_qhi (phases A,B)   } aliased by s_f (8960 B, phases D,E)
//   [8448   .. 16895]  s_qlo (phases A,B)   }
//   [16896  .. 23295]  s_l   [16][100] f32  (phases B,C)
//   [23296  .. 31743]  s_rw  [16*132] f32   (phases C,D)
//   [31744  .. 35967]  s_ri  [16*132] u16   (phases C,D)
#define SM_TOTAL 35968

typedef short s16x8 __attribute__((ext_vector_type(8)));
typedef float f32x4 __attribute__((ext_vector_type(4)));

static __device__ __forceinline__ unsigned short f2bf(float f) {
    unsigned int x = __float_as_uint(f);
    unsigned int r = x + 0x7FFFu + ((x >> 16) & 1u);   // RNE
    return (unsigned short)(r >> 16);
}
static __device__ __forceinline__ float bf2f(unsigned short h) {
    return __uint_as_float(((unsigned int)h) << 16);
}

// ============ Kernel 0: pack weights ============
__global__ __launch_bounds__(256) void pack_kernel(
    const float* __restrict__ w_off,   // [256,64]
    const float* __restrict__ w_wt,    // [256,32]
    const float* __restrict__ w_out,   // [256,256]
    unsigned short* __restrict__ Wp_hi,
    unsigned short* __restrict__ Wp_lo,
    unsigned short* __restrict__ Bp)
{
    const int t = threadIdx.x, blk = blockIdx.x;
    if (blk < 32) {
        const int g = blk * 256 + t;          // 0..8191
        const int n = g & 255, kg = g >> 8;
        unsigned int w[4];
        #pragma unroll
        for (int jj = 0; jj < 4; ++jj) {
            const unsigned int lo = f2bf(w_out[(size_t)(kg * 8 + jj * 2 + 0) * CC + n]);
            const unsigned int hi = f2bf(w_out[(size_t)(kg * 8 + jj * 2 + 1) * CC + n]);
            w[jj] = lo | (hi << 16);
        }
        uint4 v; v.x = w[0]; v.y = w[1]; v.z = w[2]; v.w = w[3];
        *(uint4*)&Bp[(size_t)g * 8] = v;
    } else {
        const int gid = (blk - 32) * 256 + t;  // 0..3071
        const int kg = gid / 96, n = gid - kg * 96;
        unsigned int wh[4], wl[4];
        #pragma unroll
        for (int jj = 0; jj < 4; ++jj) {
            unsigned int hp[2], lp[2];
            #pragma unroll
            for (int s = 0; s < 2; ++s) {
                const int k = kg * 8 + jj * 2 + s;
                const float w = (n < 64) ? w_off[(size_t)k * 64 + n]
                                         : w_wt[(size_t)k * 32 + (n - 64)];
                const unsigned short h = f2bf(w);
                hp[s] = h;
                lp[s] = f2bf(w - bf2f(h));
            }
            wh[jj] = hp[0] | (hp[1] << 16);
            wl[jj] = lp[0] | (lp[1] << 16);
        }
        uint4 vh; vh.x = wh[0]; vh.y = wh[1]; vh.z = wh[2]; vh.w = wh[3];
        uint4 vl; vl.x = wl[0]; vl.y = wl[1]; vl.z = wl[2]; vl.w = wl[3];
        *(uint4*)&Wp_hi[(size_t)gid * 8] = vh;
        *(uint4*)&Wp_lo[(size_t)gid * 8] = vl;
    }
}

// ============ Kernel 1: fused proj(bf16x3 MFMA) + transform + gather + out-MFMA ============
__global__ __launch_bounds__(256, 3) void fused_kernel(
    const float* __restrict__ query,     // [M,256]
    const float* __restrict__ refpts,    // [M,2]
    const float* __restrict__ memory,    // [B,HW,256]
    const float* __restrict__ b_off,     // [64]
    const float* __restrict__ b_wt,      // [32]
    const float* __restrict__ b_out,     // [256]
    const unsigned short* __restrict__ Wp_hi,
    const unsigned short* __restrict__ Wp_lo,
    const unsigned short* __restrict__ Bp,
    float* __restrict__ out)             // [M,256]
{
    const int t = threadIdx.x;
    const int bn0 = blockIdx.x * SR;
    const int lane = t & 63, wid = t >> 6;
    const int lr = lane & 15, lg = lane >> 4;

    __shared__ __align__(16) char smem[SM_TOTAL];
    unsigned short* s_qhi = (unsigned short*)smem;
    unsigned short* s_qlo = (unsigned short*)(smem + 8448);
    unsigned short* s_f   = (unsigned short*)smem;            // alias (used after B)
    float (*s_l)[100]     = (float (*)[100])(smem + 16896);
    float* s_rw           = (float*)(smem + 23296);
    unsigned short* s_ri  = (unsigned short*)(smem + 31744);

    // ---- Phase A: load query rows, split into bf16 hi/lo ----
    #pragma unroll
    for (int j = 0; j < 4; ++j) {
        const int e4 = (t + j * 256) * 4;      // 0..4092
        const int r = e4 >> 8, c = e4 & 255;
        const float4 q = *(const float4*)&query[(size_t)(bn0 + r) * CC + c];
        ushort4 hv, lv;
        hv.x = f2bf(q.x); lv.x = f2bf(q.x - bf2f(hv.x));
        hv.y = f2bf(q.y); lv.y = f2bf(q.y - bf2f(hv.y));
        hv.z = f2bf(q.z); lv.z = f2bf(q.z - bf2f(hv.z));
        hv.w = f2bf(q.w); lv.w = f2bf(q.w - bf2f(hv.w));
        *(ushort4*)&s_qhi[r * QS + c] = hv;
        *(ushort4*)&s_qlo[r * QS + c] = lv;
    }
    __syncthreads();

    // ---- Phase B: proj GEMM via bf16x3 MFMA (waves 0..2, 2 n-tiles of 16 each) ----
    if (wid < 3) {
        f32x4 pa[2] = {};
        #pragma unroll
        for (int ks = 0; ks < 8; ++ks) {
            const s16x8 ahi = *(const s16x8*)&s_qhi[lr * QS + lg * 8 + ks * 32];
            const s16x8 alo = *(const s16x8*)&s_qlo[lr * QS + lg * 8 + ks * 32];
            #pragma unroll
            for (int n = 0; n < 2; ++n) {
                const int nt = wid * 2 + n;
                const size_t boff = ((size_t)(lg + ks * 4) * 96 + nt * 16 + lr) * 8;
                const s16x8 bhi = *(const s16x8*)&Wp_hi[boff];
                const s16x8 blo = *(const s16x8*)&Wp_lo[boff];
                pa[n] = __builtin_amdgcn_mfma_f32_16x16x32_bf16(ahi, bhi, pa[n], 0, 0, 0);
                pa[n] = __builtin_amdgcn_mfma_f32_16x16x32_bf16(ahi, blo, pa[n], 0, 0, 0);
                pa[n] = __builtin_amdgcn_mfma_f32_16x16x32_bf16(alo, bhi, pa[n], 0, 0, 0);
            }
        }
        #pragma unroll
        for (int n = 0; n < 2; ++n) {
            const int nt = wid * 2 + n;
            #pragma unroll
            for (int r = 0; r < 4; ++r)
                s_l[lg * 4 + r][nt * 16 + lr] = pa[n][r];
        }
    }
    __syncthreads();

    // ---- Phase C: transform (threads 0..127 = 16 rows x 8 heads) ----
    if (t < SR * HEADS) {
        const int r = t >> 3, h = t & 7;
        const int bn = bn0 + r;
        const float rx = refpts[(size_t)bn * 2 + 0];
        const float ry = refpts[(size_t)bn * 2 + 1];

        const float l0 = s_l[r][64 + h * 4 + 0] + b_wt[h * 4 + 0];
        const float l1 = s_l[r][64 + h * 4 + 1] + b_wt[h * 4 + 1];
        const float l2 = s_l[r][64 + h * 4 + 2] + b_wt[h * 4 + 2];
        const float l3 = s_l[r][64 + h * 4 + 3] + b_wt[h * 4 + 3];
        const float m = fmaxf(fmaxf(l0, l1), fmaxf(l2, l3));
        const float e0 = expf(l0 - m), e1 = expf(l1 - m);
        const float e2 = expf(l2 - m), e3 = expf(l3 - m);
        const float inv = 1.f / (e0 + e1 + e2 + e3);
        const float ww[4] = {e0 * inv, e1 * inv, e2 * inv, e3 * inv};

        #pragma unroll
        for (int p = 0; p < PP; ++p) {
            const float wt = ww[p];
            const float ox = tanhf(s_l[r][h * 8 + p * 2 + 0] + b_off[h * 8 + p * 2 + 0]) * RADIUS;
            const float oy = tanhf(s_l[r][h * 8 + p * 2 + 1] + b_off[h * 8 + p * 2 + 1]) * RADIUS;
            const float x = (rx + ox) * (float)BEV_W - 0.5f;
            const float y = (ry + oy) * (float)BEV_H - 0.5f;
            const float x0f = floorf(x), y0f = floorf(y);
            const int x0 = (int)x0f, y0 = (int)y0f;
            const float fx = x - x0f, fy = y - y0f;
            const bool xv0 = (unsigned)x0 < (unsigned)BEV_W;
            const bool xv1 = (unsigned)(x0 + 1) < (unsigned)BEV_W;
            const bool yv0 = (unsigned)y0 < (unsigned)BEV_H;
            const bool yv1 = (unsigned)(y0 + 1) < (unsigned)BEV_H;
            const int cx0 = min(max(x0, 0), BEV_W - 1);
            const int cx1 = min(max(x0 + 1, 0), BEV_W - 1);
            const int cy0 = min(max(y0, 0), BEV_H - 1);
            const int cy1 = min(max(y0 + 1, 0), BEV_H - 1);
            const int base = r * RS + p * 32 + h;    // (p*4+c)*8 + h, c=0..3
            s_rw[base + 0]  = (xv0 && yv0) ? wt * (1.f - fx) * (1.f - fy) : 0.f;
            s_rw[base + 8]  = (xv1 && yv0) ? wt * fx * (1.f - fy) : 0.f;
            s_rw[base + 16] = (xv0 && yv1) ? wt * (1.f - fx) * fy : 0.f;
            s_rw[base + 24] = (xv1 && yv1) ? wt * fx * fy : 0.f;
            s_ri[base + 0]  = (unsigned short)(cy0 * BEV_W + cx0);
            s_ri[base + 8]  = (unsigned short)(cy0 * BEV_W + cx1);
            s_ri[base + 16] = (unsigned short)(cy1 * BEV_W + cx0);
            s_ri[base + 24] = (unsigned short)(cy1 * BEV_W + cx1);
        }
    }
    __syncthreads();

    // ---- Phase D: bilinear gather into bf16 LDS tile (aliases s_qhi/s_qlo) ----
    {
        const int qg = t >> 6, h = (t >> 3) & 7, l8 = t & 7;
        const int coff = h * HD + l8 * 4;
        #pragma unroll
        for (int i = 0; i < 4; ++i) {
            const int ql = qg * 4 + i;
            const int bn = bn0 + ql;
            const int b = bn / NN;
            const float* mb = memory + (size_t)b * HW * CC + coff;
            float ax = 0.f, ay = 0.f, az = 0.f, aw = 0.f;
            #pragma unroll
            for (int j = 0; j < 16; ++j) {
                const float w = s_rw[ql * RS + j * 8 + h];
                const int idx = (int)s_ri[ql * RS + j * 8 + h];
                const float4 v = *(const float4*)(mb + (size_t)idx * CC);
                ax += w * v.x; ay += w * v.y; az += w * v.z; aw += w * v.w;
            }
            ushort4 o; o.x = f2bf(ax); o.y = f2bf(ay); o.z = f2bf(az); o.w = f2bf(aw);
            *(ushort4*)&s_f[ql * SFS + coff] = o;
        }
    }
    __syncthreads();

    // ---- Phase E: out-projection MFMA (4 waves x 64 cols) ----
    {
        const int n0w = wid * 64;
        f32x4 acc[4] = {};
        const unsigned short* Bb = Bp + ((size_t)lg * 256 + n0w + lr) * 8;
        const unsigned short* Ar = &s_f[lr * SFS + lg * 8];
        #pragma unroll
        for (int ks = 0; ks < 8; ++ks) {
            const s16x8 a = *(const s16x8*)(Ar + ks * 32);
            #pragma unroll
            for (int nt = 0; nt < 4; ++nt) {
                const s16x8 bv = *(const s16x8*)(Bb + (size_t)(ks * 1024 + nt * 16) * 8);
                acc[nt] = __builtin_amdgcn_mfma_f32_16x16x32_bf16(a, bv, acc[nt], 0, 0, 0);
            }
        }
        #pragma unroll
        for (int nt = 0; nt < 4; ++nt) {
            const float bo = b_out[n0w + nt * 16 + lr];
            #pragma unroll
            for (int rr = 0; rr < 4; ++rr) {
                out[(size_t)(bn0 + lg * 4 + rr) * CC + n0w + nt * 16 + lr] = acc[nt][rr] + bo;
            }
        }
    }
}

extern "C" void kernel_launch(void* const* d_in, const int* in_sizes, int n_in,
                              void* d_out, int out_size, void* d_ws, size_t ws_size,
                              hipStream_t stream) {
    const float* query  = (const float*)d_in[0];
    const float* memory = (const float*)d_in[1];
    const float* refpts = (const float*)d_in[2];
    const float* w_off  = (const float*)d_in[3];
    const float* b_off  = (const float*)d_in[4];
    const float* w_wt   = (const float*)d_in[5];
    const float* b_wt   = (const float*)d_in[6];
    const float* w_out  = (const float*)d_in[7];
    const float* b_out  = (const float*)d_in[8];

    char* ws = (char*)d_ws;
    unsigned short* Bp    = (unsigned short*)(ws);            // 65536 bf16 = 128 KB
    unsigned short* Wp_hi = (unsigned short*)(ws + 131072);   // 24576 bf16 = 48 KB
    unsigned short* Wp_lo = (unsigned short*)(ws + 180224);   // 24576 bf16 = 48 KB
    float* out = (float*)d_out;

    pack_kernel<<<44, 256, 0, stream>>>(w_off, w_wt, w_out, Wp_hi, Wp_lo, Bp);
    fused_kernel<<<M_TOT / SR, 256, 0, stream>>>(
        query, refpts, memory, b_off, b_wt, b_out, Wp_hi, Wp_lo, Bp, out);
}

// Round 7
// 35.309 us; speedup vs baseline: 2.7922x; 1.0065x over previous
//
#include <hip/hip_runtime.h>
#include <math.h>

#define BB 8
#define NN 900
#define CC 256
#define HEADS 8
#define PP 4
#define BEV_H 200
#define BEV_W 200
#define HW (BEV_H * BEV_W)
#define HD 32
#define RADIUS 0.2f
#define M_TOT (BB * NN)          // 7200

#define SR 16                    // queries per fused block
#define QS 264                   // ushort stride of s_qhi/s_qlo rows
#define RS 132                   // element stride of record rows
#define SFS 280                  // ushort stride of s_f rows

// shared-memory layout (bytes), phase-aliased (liveness: A=qload, B=projMFMA,
// C=transform, D=gather, E=outMFMA; barriers between all):
//   [0     .. 6399 ]  s_l   [16][100] f32   live B..C
//   [6400  .. 14847]  s_rw  [16*132] f32    live C..D
//   [14848 .. 23295]  s_qhi (A..B)  }  overlaid by s_f [8960 B] (D..E) at 14848
//   [23296 .. 31743]  s_qlo (A..B)  }  overlaid by s_ri [4224 B] (C..D) at 23808
#define SM_TOTAL 31744

typedef short s16x8 __attribute__((ext_vector_type(8)));
typedef float f32x4 __attribute__((ext_vector_type(4)));

static __device__ __forceinline__ unsigned short f2bf(float f) {
    unsigned int x = __float_as_uint(f);
    unsigned int r = x + 0x7FFFu + ((x >> 16) & 1u);   // RNE
    return (unsigned short)(r >> 16);
}
static __device__ __forceinline__ float bf2f(unsigned short h) {
    return __uint_as_float(((unsigned int)h) << 16);
}

// ============ Kernel 0: pack weights ============
__global__ __launch_bounds__(256) void pack_kernel(
    const float* __restrict__ w_off,   // [256,64]
    const float* __restrict__ w_wt,    // [256,32]
    const float* __restrict__ w_out,   // [256,256]
    unsigned short* __restrict__ Wp_hi,
    unsigned short* __restrict__ Wp_lo,
    unsigned short* __restrict__ Bp)
{
    const int t = threadIdx.x, blk = blockIdx.x;
    if (blk < 32) {
        const int g = blk * 256 + t;          // 0..8191
        const int n = g & 255, kg = g >> 8;
        unsigned int w[4];
        #pragma unroll
        for (int jj = 0; jj < 4; ++jj) {
            const unsigned int lo = f2bf(w_out[(size_t)(kg * 8 + jj * 2 + 0) * CC + n]);
            const unsigned int hi = f2bf(w_out[(size_t)(kg * 8 + jj * 2 + 1) * CC + n]);
            w[jj] = lo | (hi << 16);
        }
        uint4 v; v.x = w[0]; v.y = w[1]; v.z = w[2]; v.w = w[3];
        *(uint4*)&Bp[(size_t)g * 8] = v;
    } else {
        const int gid = (blk - 32) * 256 + t;  // 0..3071
        const int kg = gid / 96, n = gid - kg * 96;
        unsigned int wh[4], wl[4];
        #pragma unroll
        for (int jj = 0; jj < 4; ++jj) {
            unsigned int hp[2], lp[2];
            #pragma unroll
            for (int s = 0; s < 2; ++s) {
                const int k = kg * 8 + jj * 2 + s;
                const float w = (n < 64) ? w_off[(size_t)k * 64 + n]
                                         : w_wt[(size_t)k * 32 + (n - 64)];
                const unsigned short h = f2bf(w);
                hp[s] = h;
                lp[s] = f2bf(w - bf2f(h));
            }
            wh[jj] = hp[0] | (hp[1] << 16);
            wl[jj] = lp[0] | (lp[1] << 16);
        }
        uint4 vh; vh.x = wh[0]; vh.y = wh[1]; vh.z = wh[2]; vh.w = wh[3];
        uint4 vl; vl.x = wl[0]; vl.y = wl[1]; vl.z = wl[2]; vl.w = wl[3];
        *(uint4*)&Wp_hi[(size_t)gid * 8] = vh;
        *(uint4*)&Wp_lo[(size_t)gid * 8] = vl;
    }
}

// ============ Kernel 1: fused proj(bf16x3 MFMA) + transform + gather + out-MFMA ============
__global__ __launch_bounds__(256, 4) void fused_kernel(
    const float* __restrict__ query,     // [M,256]
    const float* __restrict__ refpts,    // [M,2]
    const float* __restrict__ memory,    // [B,HW,256]
    const float* __restrict__ b_off,     // [64]
    const float* __restrict__ b_wt,      // [32]
    const float* __restrict__ b_out,     // [256]
    const unsigned short* __restrict__ Wp_hi,
    const unsigned short* __restrict__ Wp_lo,
    const unsigned short* __restrict__ Bp,
    float* __restrict__ out)             // [M,256]
{
    const int t = threadIdx.x;
    const int bn0 = blockIdx.x * SR;
    const int lane = t & 63, wid = t >> 6;
    const int lr = lane & 15, lg = lane >> 4;

    __shared__ __align__(16) char smem[SM_TOTAL];
    float (*s_l)[100]     = (float (*)[100])(smem);           // live B..C
    float* s_rw           = (float*)(smem + 6400);            // live C..D
    unsigned short* s_qhi = (unsigned short*)(smem + 14848);  // live A..B
    unsigned short* s_qlo = (unsigned short*)(smem + 23296);  // live A..B
    unsigned short* s_f   = (unsigned short*)(smem + 14848);  // live D..E (over qhi)
    unsigned short* s_ri  = (unsigned short*)(smem + 23808);  // live C..D (over qlo)

    // ---- Phase A: load query rows, split into bf16 hi/lo ----
    #pragma unroll
    for (int j = 0; j < 4; ++j) {
        const int e4 = (t + j * 256) * 4;      // 0..4092
        const int r = e4 >> 8, c = e4 & 255;
        const float4 q = *(const float4*)&query[(size_t)(bn0 + r) * CC + c];
        ushort4 hv, lv;
        hv.x = f2bf(q.x); lv.x = f2bf(q.x - bf2f(hv.x));
        hv.y = f2bf(q.y); lv.y = f2bf(q.y - bf2f(hv.y));
        hv.z = f2bf(q.z); lv.z = f2bf(q.z - bf2f(hv.z));
        hv.w = f2bf(q.w); lv.w = f2bf(q.w - bf2f(hv.w));
        *(ushort4*)&s_qhi[r * QS + c] = hv;
        *(ushort4*)&s_qlo[r * QS + c] = lv;
    }
    __syncthreads();

    // ---- Phase B: proj GEMM via bf16x3 MFMA (waves 0..2, 2 n-tiles of 16 each) ----
    if (wid < 3) {
        f32x4 pa[2] = {};
        #pragma unroll
        for (int ks = 0; ks < 8; ++ks) {
            const s16x8 ahi = *(const s16x8*)&s_qhi[lr * QS + lg * 8 + ks * 32];
            const s16x8 alo = *(const s16x8*)&s_qlo[lr * QS + lg * 8 + ks * 32];
            #pragma unroll
            for (int n = 0; n < 2; ++n) {
                const int nt = wid * 2 + n;
                const size_t boff = ((size_t)(lg + ks * 4) * 96 + nt * 16 + lr) * 8;
                const s16x8 bhi = *(const s16x8*)&Wp_hi[boff];
                const s16x8 blo = *(const s16x8*)&Wp_lo[boff];
                pa[n] = __builtin_amdgcn_mfma_f32_16x16x32_bf16(ahi, bhi, pa[n], 0, 0, 0);
                pa[n] = __builtin_amdgcn_mfma_f32_16x16x32_bf16(ahi, blo, pa[n], 0, 0, 0);
                pa[n] = __builtin_amdgcn_mfma_f32_16x16x32_bf16(alo, bhi, pa[n], 0, 0, 0);
            }
        }
        #pragma unroll
        for (int n = 0; n < 2; ++n) {
            const int nt = wid * 2 + n;
            #pragma unroll
            for (int r = 0; r < 4; ++r)
                s_l[lg * 4 + r][nt * 16 + lr] = pa[n][r];
        }
    }
    __syncthreads();

    // ---- Phase C: transform (threads 0..127 = 16 rows x 8 heads) ----
    if (t < SR * HEADS) {
        const int r = t >> 3, h = t & 7;
        const int bn = bn0 + r;
        const float rx = refpts[(size_t)bn * 2 + 0];
        const float ry = refpts[(size_t)bn * 2 + 1];

        const float l0 = s_l[r][64 + h * 4 + 0] + b_wt[h * 4 + 0];
        const float l1 = s_l[r][64 + h * 4 + 1] + b_wt[h * 4 + 1];
        const float l2 = s_l[r][64 + h * 4 + 2] + b_wt[h * 4 + 2];
        const float l3 = s_l[r][64 + h * 4 + 3] + b_wt[h * 4 + 3];
        const float m = fmaxf(fmaxf(l0, l1), fmaxf(l2, l3));
        const float e0 = expf(l0 - m), e1 = expf(l1 - m);
        const float e2 = expf(l2 - m), e3 = expf(l3 - m);
        const float inv = 1.f / (e0 + e1 + e2 + e3);
        const float ww[4] = {e0 * inv, e1 * inv, e2 * inv, e3 * inv};

        #pragma unroll
        for (int p = 0; p < PP; ++p) {
            const float wt = ww[p];
            const float ox = tanhf(s_l[r][h * 8 + p * 2 + 0] + b_off[h * 8 + p * 2 + 0]) * RADIUS;
            const float oy = tanhf(s_l[r][h * 8 + p * 2 + 1] + b_off[h * 8 + p * 2 + 1]) * RADIUS;
            const float x = (rx + ox) * (float)BEV_W - 0.5f;
            const float y = (ry + oy) * (float)BEV_H - 0.5f;
            const float x0f = floorf(x), y0f = floorf(y);
            const int x0 = (int)x0f, y0 = (int)y0f;
            const float fx = x - x0f, fy = y - y0f;
            const bool xv0 = (unsigned)x0 < (unsigned)BEV_W;
            const bool xv1 = (unsigned)(x0 + 1) < (unsigned)BEV_W;
            const bool yv0 = (unsigned)y0 < (unsigned)BEV_H;
            const bool yv1 = (unsigned)(y0 + 1) < (unsigned)BEV_H;
            const int cx0 = min(max(x0, 0), BEV_W - 1);
            const int cx1 = min(max(x0 + 1, 0), BEV_W - 1);
            const int cy0 = min(max(y0, 0), BEV_H - 1);
            const int cy1 = min(max(y0 + 1, 0), BEV_H - 1);
            const int base = r * RS + p * 32 + h;    // (p*4+c)*8 + h, c=0..3
            s_rw[base + 0]  = (xv0 && yv0) ? wt * (1.f - fx) * (1.f - fy) : 0.f;
            s_rw[base + 8]  = (xv1 && yv0) ? wt * fx * (1.f - fy) : 0.f;
            s_rw[base + 16] = (xv0 && yv1) ? wt * (1.f - fx) * fy : 0.f;
            s_rw[base + 24] = (xv1 && yv1) ? wt * fx * fy : 0.f;
            s_ri[base + 0]  = (unsigned short)(cy0 * BEV_W + cx0);
            s_ri[base + 8]  = (unsigned short)(cy0 * BEV_W + cx1);
            s_ri[base + 16] = (unsigned short)(cy1 * BEV_W + cx0);
            s_ri[base + 24] = (unsigned short)(cy1 * BEV_W + cx1);
        }
    }
    __syncthreads();

    // ---- Phase D: bilinear gather into bf16 LDS tile (s_f over dead s_qhi) ----
    {
        const int qg = t >> 6, h = (t >> 3) & 7, l8 = t & 7;
        const int coff = h * HD + l8 * 4;
        #pragma unroll
        for (int i = 0; i < 4; ++i) {
            const int ql = qg * 4 + i;
            const int bn = bn0 + ql;
            const int b = bn / NN;
            const float* mb = memory + (size_t)b * HW * CC + coff;
            float ax = 0.f, ay = 0.f, az = 0.f, aw = 0.f;
            #pragma unroll
            for (int j = 0; j < 16; ++j) {
                const float w = s_rw[ql * RS + j * 8 + h];
                const int idx = (int)s_ri[ql * RS + j * 8 + h];
                const float4 v = *(const float4*)(mb + (size_t)idx * CC);
                ax += w * v.x; ay += w * v.y; az += w * v.z; aw += w * v.w;
            }
            ushort4 o; o.x = f2bf(ax); o.y = f2bf(ay); o.z = f2bf(az); o.w = f2bf(aw);
            *(ushort4*)&s_f[ql * SFS + coff] = o;
        }
    }
    __syncthreads();

    // ---- Phase E: out-projection MFMA (4 waves x 64 cols) ----
    {
        const int n0w = wid * 64;
        f32x4 acc[4] = {};
        const unsigned short* Bb = Bp + ((size_t)lg * 256 + n0w + lr) * 8;
        const unsigned short* Ar = &s_f[lr * SFS + lg * 8];
        #pragma unroll
        for (int ks = 0; ks < 8; ++ks) {
            const s16x8 a = *(const s16x8*)(Ar + ks * 32);
            #pragma unroll
            for (int nt = 0; nt < 4; ++nt) {
                const s16x8 bv = *(const s16x8*)(Bb + (size_t)(ks * 1024 + nt * 16) * 8);
                acc[nt] = __builtin_amdgcn_mfma_f32_16x16x32_bf16(a, bv, acc[nt], 0, 0, 0);
            }
        }
        #pragma unroll
        for (int nt = 0; nt < 4; ++nt) {
            const float bo = b_out[n0w + nt * 16 + lr];
            #pragma unroll
            for (int rr = 0; rr < 4; ++rr) {
                out[(size_t)(bn0 + lg * 4 + rr) * CC + n0w + nt * 16 + lr] = acc[nt][rr] + bo;
            }
        }
    }
}

extern "C" void kernel_launch(void* const* d_in, const int* in_sizes, int n_in,
                              void* d_out, int out_size, void* d_ws, size_t ws_size,
                              hipStream_t stream) {
    const float* query  = (const float*)d_in[0];
    const float* memory = (const float*)d_in[1];
    const float* refpts = (const float*)d_in[2];
    const float* w_off  = (const float*)d_in[3];
    const float* b_off  = (const float*)d_in[4];
    const float* w_wt   = (const float*)d_in[5];
    const float* b_wt   = (const float*)d_in[6];
    const float* w_out  = (const float*)d_in[7];
    const float* b_out  = (const float*)d_in[8];

    char* ws = (char*)d_ws;
    unsigned short* Bp    = (unsigned short*)(ws);            // 65536 bf16 = 128 KB
    unsigned short* Wp_hi = (unsigned short*)(ws + 131072);   // 24576 bf16 = 48 KB
    unsigned short* Wp_lo = (unsigned short*)(ws + 180224);   // 24576 bf16 = 48 KB
    float* out = (float*)d_out;

    pack_kernel<<<44, 256, 0, stream>>>(w_off, w_wt, w_out, Wp_hi, Wp_lo, Bp);
    fused_kernel<<<M_TOT / SR, 256, 0, stream>>>(
        query, refpts, memory, b_off, b_wt, b_out, Wp_hi, Wp_lo, Bp, out);
}